// Round 1
// baseline (240.468 us; speedup 1.0000x reference)
//
#include <hip/hip_runtime.h>
#include <stdint.h>

#define S_LEN 2048
#define DMODEL 1024
#define NBATCH 4
#define MROWS (NBATCH * S_LEN)  // 8192

typedef __bf16 bf16x8 __attribute__((ext_vector_type(8)));
typedef float f32x4 __attribute__((ext_vector_type(4)));

__device__ __forceinline__ unsigned short f2bf(float f) {
  unsigned int x = __builtin_bit_cast(unsigned int, f);
  x += 0x7FFFu + ((x >> 16) & 1u);
  return (unsigned short)(x >> 16);
}

// ---------------- convert f32 -> bf16 (vectorized) ----------------
__global__ void cvt_kernel(const float* __restrict__ src, ushort4* __restrict__ dst, int n4) {
  int i = blockIdx.x * blockDim.x + threadIdx.x;
  if (i < n4) {
    float4 v = reinterpret_cast<const float4*>(src)[i];
    ushort4 o;
    o.x = f2bf(v.x); o.y = f2bf(v.y); o.z = f2bf(v.z); o.w = f2bf(v.w);
    dst[i] = o;
  }
}

// ---------------- GEMM: C = A * B^T ----------------
// A: [M x K] bf16 row-major (lda=K); Bm: [N x K] bf16 row-major (ldb=K)
// m97 structure: 128x128 tile, BK=64, 4 waves (2x2), 16x16x32 bf16 MFMA,
// global_load_lds width=16 staging, 2 barriers per K-step.
// EP: 0 = bf16 out + bias; 1 = f32 out * scale; 2 = f32 out
#define BM 128
#define BN 128
#define BK 64

template <int EP>
__global__ __launch_bounds__(256) void gemm_bt(
    const unsigned short* __restrict__ A, const unsigned short* __restrict__ Bm,
    void* __restrict__ Cp, const float* __restrict__ bias,
    int M, int N, int K, float scale, long zsA, long zsB, long zsC) {
  __shared__ alignas(16) char lds[BM * BK * 2 + BN * BK * 2];  // 16KB + 16KB
  char* Alds = lds;
  char* Blds = lds + BM * BK * 2;

  const int tid = threadIdx.x;
  const int lane = tid & 63;
  const int wid = tid >> 6;  // 0..3
  const int wr = wid >> 1, wc = wid & 1;

  const int z = blockIdx.z;
  const unsigned short* Ab = A + (size_t)z * zsA;
  const unsigned short* Bb = Bm + (size_t)z * zsB;

  const int tileN = blockIdx.x * BN;
  const int tileM = blockIdx.y * BM;

  f32x4 acc[4][4];
#pragma unroll
  for (int m = 0; m < 4; ++m)
#pragma unroll
    for (int n = 0; n < 4; ++n) acc[m][n] = f32x4{0.f, 0.f, 0.f, 0.f};

  const int rA = lane >> 3;         // row within 8-row chunk
  const int cA = (lane & 7) * 16;   // byte within 128B row

  for (int k0 = 0; k0 < K; k0 += BK) {
    // stage A tile (128 rows x 64 bf16 = 16KB, 16 chunks of 1KB; wave w does chunks w*4..w*4+3)
#pragma unroll
    for (int i = 0; i < 4; ++i) {
      int c = wid * 4 + i;
      const char* g = (const char*)(Ab + (size_t)(tileM + c * 8 + rA) * K + k0) + cA;
      __builtin_amdgcn_global_load_lds(
          (const __attribute__((address_space(1))) void*)g,
          (__attribute__((address_space(3))) void*)(Alds + c * 1024), 16, 0, 0);
    }
#pragma unroll
    for (int i = 0; i < 4; ++i) {
      int c = wid * 4 + i;
      const char* g = (const char*)(Bb + (size_t)(tileN + c * 8 + rA) * K + k0) + cA;
      __builtin_amdgcn_global_load_lds(
          (const __attribute__((address_space(1))) void*)g,
          (__attribute__((address_space(3))) void*)(Blds + c * 1024), 16, 0, 0);
    }
    __syncthreads();

#pragma unroll
    for (int kk = 0; kk < 2; ++kk) {
      bf16x8 av[4], bv[4];
#pragma unroll
      for (int m = 0; m < 4; ++m) {
        int row = wr * 64 + m * 16 + (lane & 15);
        av[m] = *reinterpret_cast<const bf16x8*>(Alds + row * 128 + kk * 64 + (lane >> 4) * 16);
      }
#pragma unroll
      for (int n = 0; n < 4; ++n) {
        int row = wc * 64 + n * 16 + (lane & 15);
        bv[n] = *reinterpret_cast<const bf16x8*>(Blds + row * 128 + kk * 64 + (lane >> 4) * 16);
      }
#pragma unroll
      for (int m = 0; m < 4; ++m)
#pragma unroll
        for (int n = 0; n < 4; ++n)
          acc[m][n] = __builtin_amdgcn_mfma_f32_16x16x32_bf16(av[m], bv[n], acc[m][n], 0, 0, 0);
    }
    __syncthreads();
  }

  // epilogue: C/D layout (m89-verified): col = lane&15, row = (lane>>4)*4 + j
  const int lr = (lane >> 4) * 4;
  const int lc = lane & 15;
#pragma unroll
  for (int m = 0; m < 4; ++m) {
#pragma unroll
    for (int n = 0; n < 4; ++n) {
      int gr = tileM + wr * 64 + m * 16 + lr;
      int gc = tileN + wc * 64 + n * 16 + lc;
      f32x4 v = acc[m][n];
      if (EP == 0) {
        float bb = bias[gc];
        unsigned short* C = (unsigned short*)Cp + (size_t)z * zsC;
#pragma unroll
        for (int j = 0; j < 4; ++j) C[(size_t)(gr + j) * N + gc] = f2bf(v[j] + bb);
      } else {
        float* C = (float*)Cp + (size_t)z * zsC;
#pragma unroll
        for (int j = 0; j < 4; ++j) C[(size_t)(gr + j) * N + gc] = (EP == 1) ? v[j] * scale : v[j];
      }
    }
  }
}

// ---------------- transpose bf16 [S x D] -> [D x S] per batch ----------------
__global__ void transpose_kernel(const unsigned short* __restrict__ src,
                                 unsigned short* __restrict__ dst) {
  __shared__ unsigned short tile[32][33];
  int b = blockIdx.z;
  int s0 = blockIdx.x * 32;
  int d0 = blockIdx.y * 32;
  int t = threadIdx.x;
  int r = t >> 3;          // 0..31
  int c4 = (t & 7) * 4;    // 0..28
  const unsigned short* sp = src + ((size_t)b * S_LEN + s0 + r) * DMODEL + d0 + c4;
  ushort4 v = *reinterpret_cast<const ushort4*>(sp);
  tile[r][c4 + 0] = v.x; tile[r][c4 + 1] = v.y; tile[r][c4 + 2] = v.z; tile[r][c4 + 3] = v.w;
  __syncthreads();
  unsigned short* dp = dst + ((size_t)b * DMODEL + d0 + r) * S_LEN + s0 + c4;
  ushort4 o;
  o.x = tile[c4 + 0][r]; o.y = tile[c4 + 1][r]; o.z = tile[c4 + 2][r]; o.w = tile[c4 + 3][r];
  *reinterpret_cast<ushort4*>(dp) = o;
}

// ---------------- row softmax: fp32 [8192 x 2048] -> bf16 P ----------------
__global__ __launch_bounds__(256) void softmax_kernel(const float* __restrict__ Sb,
                                                      unsigned short* __restrict__ P) {
  const size_t row = blockIdx.x;
  const float* sp = Sb + row * S_LEN;
  const int t = threadIdx.x;
  const int wid = t >> 6, lane = t & 63;
  float4 v0 = reinterpret_cast<const float4*>(sp)[t * 2];
  float4 v1 = reinterpret_cast<const float4*>(sp)[t * 2 + 1];
  float s[8] = {v0.x, v0.y, v0.z, v0.w, v1.x, v1.y, v1.z, v1.w};
  float mx = s[0];
#pragma unroll
  for (int i = 1; i < 8; ++i) mx = fmaxf(mx, s[i]);
#pragma unroll
  for (int o = 32; o > 0; o >>= 1) mx = fmaxf(mx, __shfl_xor(mx, o));
  __shared__ float redm[4];
  __shared__ float reds[4];
  if (lane == 0) redm[wid] = mx;
  __syncthreads();
  mx = fmaxf(fmaxf(redm[0], redm[1]), fmaxf(redm[2], redm[3]));
  float e[8];
  float sum = 0.f;
#pragma unroll
  for (int i = 0; i < 8; ++i) { e[i] = __expf(s[i] - mx); sum += e[i]; }
#pragma unroll
  for (int o = 32; o > 0; o >>= 1) sum += __shfl_xor(sum, o);
  if (lane == 0) reds[wid] = sum;
  __syncthreads();
  sum = reds[0] + reds[1] + reds[2] + reds[3];
  float inv = 1.0f / sum;
  ushort4 o0, o1;
  o0.x = f2bf(e[0] * inv); o0.y = f2bf(e[1] * inv); o0.z = f2bf(e[2] * inv); o0.w = f2bf(e[3] * inv);
  o1.x = f2bf(e[4] * inv); o1.y = f2bf(e[5] * inv); o1.z = f2bf(e[6] * inv); o1.w = f2bf(e[7] * inv);
  ushort4* dp = reinterpret_cast<ushort4*>(P + row * S_LEN);
  dp[t * 2] = o0;
  dp[t * 2 + 1] = o1;
}

extern "C" void kernel_launch(void* const* d_in, const int* in_sizes, int n_in,
                              void* d_out, int out_size, void* d_ws, size_t ws_size,
                              hipStream_t stream) {
  (void)in_sizes; (void)n_in; (void)out_size;
  const float* x = (const float*)d_in[0];
  const float* Wq = (const float*)d_in[1];
  const float* bq = (const float*)d_in[2];
  const float* Wk = (const float*)d_in[3];
  const float* bk = (const float*)d_in[4];
  const float* Wv = (const float*)d_in[5];
  const float* bv = (const float*)d_in[6];
  float* out = (float*)d_out;

  // workspace layout (bytes):
  //   xb   [8192x1024 bf16]  @ 0          (16 MB)   -- reused as Vt after projections
  //   Wqb/Wkb/Wvb bf16       @ 16 MB      (3 x 2 MB)
  //   Qb   [8192x1024 bf16]  @ 22.25 MB   (16 MB)   -- Qb..Kb reused as P after scores
  //   Kb                      +16 MB
  //   Vb                      +16 MB
  //   Sb   [4x2048x2048 f32] @ 70 MB      (64 MB)
  // total = 140,509,184 bytes
  if (ws_size < 140509184ull) return;  // insufficient scratch; fail validation cleanly
  char* ws = (char*)d_ws;
  unsigned short* xb  = (unsigned short*)(ws);
  unsigned short* Wqb = (unsigned short*)(ws + 16777216);
  unsigned short* Wkb = (unsigned short*)(ws + 16777216 + 2097152);
  unsigned short* Wvb = (unsigned short*)(ws + 16777216 + 2 * 2097152);
  unsigned short* Qb  = (unsigned short*)(ws + 16777216 + 3 * 2097152);
  unsigned short* Kb  = (unsigned short*)(ws + 16777216 + 3 * 2097152 + 16777216);
  unsigned short* Vb  = (unsigned short*)(ws + 16777216 + 3 * 2097152 + 2 * 16777216);
  float* Sb           = (float*)(ws + 16777216 + 3 * 2097152 + 3 * 16777216);
  unsigned short* Vtb = xb;  // safe: transpose launched after last use of xb
  unsigned short* P   = Qb;  // safe: softmax launched after last use of Qb/Kb; spans both

  // 1) converts to bf16
  cvt_kernel<<<dim3(MROWS * DMODEL / 4 / 256), 256, 0, stream>>>(x, (ushort4*)xb, MROWS * DMODEL / 4);
  cvt_kernel<<<dim3(DMODEL * DMODEL / 4 / 256), 256, 0, stream>>>(Wq, (ushort4*)Wqb, DMODEL * DMODEL / 4);
  cvt_kernel<<<dim3(DMODEL * DMODEL / 4 / 256), 256, 0, stream>>>(Wk, (ushort4*)Wkb, DMODEL * DMODEL / 4);
  cvt_kernel<<<dim3(DMODEL * DMODEL / 4 / 256), 256, 0, stream>>>(Wv, (ushort4*)Wvb, DMODEL * DMODEL / 4);

  // 2) projections: Q/K/V = x * W^T + b  (M=8192, N=1024, K=1024)
  dim3 gp(DMODEL / BN, MROWS / BM, 1);
  gemm_bt<0><<<gp, 256, 0, stream>>>(xb, Wqb, Qb, bq, MROWS, DMODEL, DMODEL, 1.f, 0, 0, 0);
  gemm_bt<0><<<gp, 256, 0, stream>>>(xb, Wkb, Kb, bk, MROWS, DMODEL, DMODEL, 1.f, 0, 0, 0);
  gemm_bt<0><<<gp, 256, 0, stream>>>(xb, Wvb, Vb, bv, MROWS, DMODEL, DMODEL, 1.f, 0, 0, 0);

  // 3) transpose V -> Vt [D x S] per batch
  transpose_kernel<<<dim3(S_LEN / 32, DMODEL / 32, NBATCH), 256, 0, stream>>>(Vb, Vtb);

  // 4) scores: S = Q * K^T * 0.125  (per batch: M=N=2048, K=1024)
  dim3 gs(S_LEN / BN, S_LEN / BM, NBATCH);
  gemm_bt<1><<<gs, 256, 0, stream>>>(Qb, Kb, Sb, nullptr, S_LEN, S_LEN, DMODEL, 0.125f,
                                     (long)S_LEN * DMODEL, (long)S_LEN * DMODEL,
                                     (long)S_LEN * S_LEN);

  // 5) row softmax -> bf16 P
  softmax_kernel<<<dim3(NBATCH * S_LEN), 256, 0, stream>>>(Sb, P);

  // 6) out = P * Vt^T  (per batch: M=2048, N=1024, K=2048)
  dim3 go(DMODEL / BN, S_LEN / BM, NBATCH);
  gemm_bt<2><<<go, 256, 0, stream>>>(P, Vtb, out, nullptr, S_LEN, DMODEL, S_LEN, 1.f,
                                     (long)S_LEN * S_LEN, (long)DMODEL * S_LEN,
                                     (long)S_LEN * DMODEL);
}

// Round 3
// 204.574 us; speedup vs baseline: 1.1755x; 1.1755x over previous
//
#include <hip/hip_runtime.h>
#include <stdint.h>

#define S_LEN 2048
#define DMODEL 1024
#define NBATCH 4
#define MROWS (NBATCH * S_LEN)  // 8192

typedef __bf16 bf16x8 __attribute__((ext_vector_type(8)));
typedef float f32x4 __attribute__((ext_vector_type(4)));

__device__ __forceinline__ unsigned short f2bf(float f) {
  unsigned int x = __builtin_bit_cast(unsigned int, f);
  x += 0x7FFFu + ((x >> 16) & 1u);
  return (unsigned short)(x >> 16);
}

template <int N>
__device__ __forceinline__ void waitvm() {
  static_assert(N >= 0 && N <= 8, "vmcnt range");
  if constexpr (N == 0) asm volatile("s_waitcnt vmcnt(0)" ::: "memory");
  else if constexpr (N == 1) asm volatile("s_waitcnt vmcnt(1)" ::: "memory");
  else if constexpr (N == 2) asm volatile("s_waitcnt vmcnt(2)" ::: "memory");
  else if constexpr (N == 3) asm volatile("s_waitcnt vmcnt(3)" ::: "memory");
  else if constexpr (N == 4) asm volatile("s_waitcnt vmcnt(4)" ::: "memory");
  else if constexpr (N == 5) asm volatile("s_waitcnt vmcnt(5)" ::: "memory");
  else if constexpr (N == 6) asm volatile("s_waitcnt vmcnt(6)" ::: "memory");
  else if constexpr (N == 7) asm volatile("s_waitcnt vmcnt(7)" ::: "memory");
  else asm volatile("s_waitcnt vmcnt(8)" ::: "memory");
}
#define BARRIER() do { __builtin_amdgcn_s_barrier(); asm volatile("" ::: "memory"); } while (0)

// ---------------- convert f32 -> bf16 (vectorized) ----------------
__global__ void cvt_kernel(const float* __restrict__ src, ushort4* __restrict__ dst, int n4) {
  int i = blockIdx.x * blockDim.x + threadIdx.x;
  if (i < n4) {
    float4 v = reinterpret_cast<const float4*>(src)[i];
    ushort4 o;
    o.x = f2bf(v.x); o.y = f2bf(v.y); o.z = f2bf(v.z); o.w = f2bf(v.w);
    dst[i] = o;
  }
}

// ---------------- 8-phase GEMM: C = A * B^T ----------------
// A: [M x K] bf16 row-major (lda); Bm: [N x K] bf16 row-major (ldb).
// 512 threads = 8 waves (2M x 4N). BN=256 fixed, BM in {128,256}. BK=64.
// Per K-tile: 4 phases = {stage 1 half-tile of t+1, counted vmcnt, barrier,
// ds_read quadrant frags (XOR-swizzled), setprio+MFMA, barrier}.
// Stage order [A0,B0,A1,B1]; quadrant order [(0,0),(1,0),(1,1),(0,1)].
// CRITICAL (round-2 bug fix): quadrant (mh,nh) must read EXACTLY the staged
// contiguous halves across ALL waves:
//   A row = mh*(BM/2) + wm*(BM/4) + m*16 + frow   -> quadrant mh == A-half mh
//   B row = nh*128    + wn*32     + nn*16 + frow  -> quadrant nh == B-half nh
// Each wave owns two strided output strips; epilogue uses the same mapping.
// LDS swizzle: 16B-slot index ^= (row&7), applied via pre-swizzled GLOBAL
// source (linear LDS dest, rule #21) and identically on ds_read.
// EP: 0 = bf16 out + bias[col]; 1 = f32 out * scale; 2 = f32 out
template <int BM_, int EP>
__global__ __launch_bounds__(512, 2) void gemm8(
    const unsigned short* __restrict__ A, const unsigned short* __restrict__ Bm,
    void* __restrict__ Cp, const float* __restrict__ bias,
    int lda, int ldb, int ldc, int NT, float scale,
    long zsA, long zsB, long zsC) {
  constexpr int BN_ = 256;
  constexpr int BK = 64;                 // elements (128 bytes)
  constexpr int RA = BM_ / 128;          // stage loads per A-half per wave
  constexpr int HALF_A = (BM_ / 2) * 128;  // bytes
  constexpr int HALF_B = 128 * 128;
  constexpr int ATILE = BM_ * 128;
  constexpr int BTILE = BN_ * 128;
  constexpr int MREP = BM_ / 32;         // 8 or 4
  constexpr int MQ = MREP / 2;           // A frags per quadrant (4 or 2)
  constexpr int VM_A = 2 * RA + 2;       // steady vmcnt at A-stage phases
  constexpr int VM_B = RA + 4;           // steady vmcnt at B-stage phases

  __shared__ alignas(16) char lds[(ATILE + BTILE) * 2];

  const int tid = threadIdx.x;
  const int l = tid & 63;
  const int w = tid >> 6;   // 0..7
  const int wm = w >> 2;    // 0..1
  const int wn = w & 3;     // 0..3

  // bijective XCD-chunked swizzle (nwg % 8 == 0 for all our grids)
  const int gx = gridDim.x;
  const int nwg = gridDim.x * gridDim.y;
  int n = blockIdx.y * gx + blockIdx.x;
  int n2 = (n & 7) * (nwg >> 3) + (n >> 3);
  const int tileM = (n2 / gx) * BM_;
  const int tileN = (n2 % gx) * BN_;

  const int z = blockIdx.z;
  const unsigned short* Ab = A + (size_t)z * zsA;
  const unsigned short* Bb = Bm + (size_t)z * zsB;

  // staging: per-lane pre-swizzled global col; linear LDS dest (wave-uniform base)
  const int srow = l >> 3;                       // 0..7 within 8-row wave chunk
  const int scol = (((l & 7) ^ srow) * 16);      // swizzled byte col within 128B row

  auto stageA = [&](int buf, int t, int h) {
#pragma unroll
    for (int r = 0; r < RA; ++r) {
      int row = h * (BM_ / 2) + r * 64 + w * 8 + srow;
      const char* g = (const char*)(Ab + (size_t)(tileM + row) * lda + t * BK) + scol;
      char* d = lds + buf * (ATILE + BTILE) + h * HALF_A + r * 8192 + w * 1024;
      __builtin_amdgcn_global_load_lds(
          (const __attribute__((address_space(1))) void*)g,
          (__attribute__((address_space(3))) void*)d, 16, 0, 0);
    }
  };
  auto stageB = [&](int buf, int t, int h) {
#pragma unroll
    for (int r = 0; r < 2; ++r) {
      int row = h * 128 + r * 64 + w * 8 + srow;
      const char* g = (const char*)(Bb + (size_t)(tileN + row) * ldb + t * BK) + scol;
      char* d = lds + buf * (ATILE + BTILE) + ATILE + h * HALF_B + r * 8192 + w * 1024;
      __builtin_amdgcn_global_load_lds(
          (const __attribute__((address_space(1))) void*)g,
          (__attribute__((address_space(3))) void*)d, 16, 0, 0);
    }
  };

  f32x4 acc[MREP][4];
#pragma unroll
  for (int m = 0; m < MREP; ++m)
#pragma unroll
    for (int nn = 0; nn < 4; ++nn) acc[m][nn] = f32x4{0.f, 0.f, 0.f, 0.f};

  // fragment ds_read (same XOR swizzle as staging; row&7 == l&7 here)
  const int frow = l & 15;
  auto rdA = [&](int buf, int mh, int m, int kk) -> bf16x8 {
    int row = mh * (BM_ / 2) + wm * (BM_ / 4) + m * 16 + frow;
    int col = (kk * 64 + ((l >> 4) * 16)) ^ ((row & 7) << 4);
    return *reinterpret_cast<const bf16x8*>(lds + buf * (ATILE + BTILE) + row * 128 + col);
  };
  auto rdB = [&](int buf, int nh, int nn, int kk) -> bf16x8 {
    int row = nh * 128 + wn * 32 + nn * 16 + frow;
    int col = (kk * 64 + ((l >> 4) * 16)) ^ ((row & 7) << 4);
    return *reinterpret_cast<const bf16x8*>(lds + buf * (ATILE + BTILE) + ATILE + row * 128 + col);
  };

  auto compute = [&](int buf, int mh, int nh) {
    bf16x8 av[MQ][2], bv[2][2];
#pragma unroll
    for (int m = 0; m < MQ; ++m)
#pragma unroll
      for (int kk = 0; kk < 2; ++kk) av[m][kk] = rdA(buf, mh, m, kk);
#pragma unroll
    for (int nn = 0; nn < 2; ++nn)
#pragma unroll
      for (int kk = 0; kk < 2; ++kk) bv[nn][kk] = rdB(buf, nh, nn, kk);
    __builtin_amdgcn_s_setprio(1);
#pragma unroll
    for (int m = 0; m < MQ; ++m)
#pragma unroll
      for (int nn = 0; nn < 2; ++nn)
#pragma unroll
        for (int kk = 0; kk < 2; ++kk)
          acc[mh * MQ + m][nh * 2 + nn] = __builtin_amdgcn_mfma_f32_16x16x32_bf16(
              av[m][kk], bv[nn][kk], acc[mh * MQ + m][nh * 2 + nn], 0, 0, 0);
    __builtin_amdgcn_s_setprio(0);
  };

  // prologue: tile 0, stage order A0,B0,A1,B1
  stageA(0, 0, 0);
  stageB(0, 0, 0);
  stageA(0, 0, 1);
  stageB(0, 0, 1);

  for (int t = 0; t < NT - 1; ++t) {
    const int buf = t & 1, nb = buf ^ 1;
    // p0: quadrant (A0,B0), stage A0(t+1)
    stageA(nb, t + 1, 0); waitvm<VM_A>(); BARRIER(); compute(buf, 0, 0); BARRIER();
    // p1: quadrant (A1,B0), stage B0(t+1)
    stageB(nb, t + 1, 0); waitvm<VM_B>(); BARRIER(); compute(buf, 1, 0); BARRIER();
    // p2: quadrant (A1,B1), stage A1(t+1)
    stageA(nb, t + 1, 1); waitvm<VM_A>(); BARRIER(); compute(buf, 1, 1); BARRIER();
    // p3: quadrant (A0,B1), stage B1(t+1)
    stageB(nb, t + 1, 1); waitvm<VM_B>(); BARRIER(); compute(buf, 0, 1); BARRIER();
  }
  {  // peeled last tile: no staging; drain counted waits
    const int buf = (NT - 1) & 1;
    waitvm<RA + 2>(); BARRIER(); compute(buf, 0, 0); BARRIER();
    waitvm<2>();      BARRIER(); compute(buf, 1, 0); BARRIER();
    waitvm<0>();      BARRIER(); compute(buf, 1, 1); BARRIER();
                      compute(buf, 0, 1);
  }

  // epilogue: C/D layout (m89): col = lane&15, row = (lane>>4)*4 + j
  // output coords use the SAME strip mapping as rdA/rdB.
  const int lr = (l >> 4) * 4;
  const int lc = l & 15;
#pragma unroll
  for (int mh = 0; mh < 2; ++mh) {
#pragma unroll
    for (int m = 0; m < MQ; ++m) {
#pragma unroll
      for (int nh = 0; nh < 2; ++nh) {
#pragma unroll
        for (int nn = 0; nn < 2; ++nn) {
          int gr = tileM + mh * (BM_ / 2) + wm * (BM_ / 4) + m * 16 + lr;
          int gc = tileN + nh * 128 + wn * 32 + nn * 16 + lc;
          f32x4 v = acc[mh * MQ + m][nh * 2 + nn];
          if constexpr (EP == 0) {
            float bb = bias[gc];
            unsigned short* C = (unsigned short*)Cp + (size_t)z * zsC;
#pragma unroll
            for (int j = 0; j < 4; ++j) C[(size_t)(gr + j) * ldc + gc] = f2bf(v[j] + bb);
          } else {
            float* C = (float*)Cp + (size_t)z * zsC;
#pragma unroll
            for (int j = 0; j < 4; ++j)
              C[(size_t)(gr + j) * ldc + gc] = (EP == 1) ? v[j] * scale : v[j];
          }
        }
      }
    }
  }
}

// ---------------- transpose bf16 V cols of QKV [S x 3072] -> Vt [D x S] per batch ----------------
__global__ void transpose_kernel(const unsigned short* __restrict__ src,
                                 unsigned short* __restrict__ dst) {
  __shared__ unsigned short tile[32][33];
  int b = blockIdx.z;
  int s0 = blockIdx.x * 32;
  int d0 = blockIdx.y * 32;
  int t = threadIdx.x;
  int r = t >> 3;
  int c4 = (t & 7) * 4;
  const unsigned short* sp = src + ((size_t)b * S_LEN + s0 + r) * 3072 + 2048 + d0 + c4;
  ushort4 v = *reinterpret_cast<const ushort4*>(sp);
  tile[r][c4 + 0] = v.x; tile[r][c4 + 1] = v.y; tile[r][c4 + 2] = v.z; tile[r][c4 + 3] = v.w;
  __syncthreads();
  unsigned short* dp = dst + ((size_t)b * DMODEL + d0 + r) * S_LEN + s0 + c4;
  ushort4 o;
  o.x = tile[c4 + 0][r]; o.y = tile[c4 + 1][r]; o.z = tile[c4 + 2][r]; o.w = tile[c4 + 3][r];
  *reinterpret_cast<ushort4*>(dp) = o;
}

// ---------------- row softmax: fp32 [8192 x 2048] -> bf16 P ----------------
__global__ __launch_bounds__(256) void softmax_kernel(const float* __restrict__ Sb,
                                                      unsigned short* __restrict__ P) {
  const size_t row = blockIdx.x;
  const float* sp = Sb + row * S_LEN;
  const int t = threadIdx.x;
  const int wid = t >> 6, lane = t & 63;
  float4 v0 = reinterpret_cast<const float4*>(sp)[t * 2];
  float4 v1 = reinterpret_cast<const float4*>(sp)[t * 2 + 1];
  float s[8] = {v0.x, v0.y, v0.z, v0.w, v1.x, v1.y, v1.z, v1.w};
  float mx = s[0];
#pragma unroll
  for (int i = 1; i < 8; ++i) mx = fmaxf(mx, s[i]);
#pragma unroll
  for (int o = 32; o > 0; o >>= 1) mx = fmaxf(mx, __shfl_xor(mx, o));
  __shared__ float redm[4];
  __shared__ float reds[4];
  if (lane == 0) redm[wid] = mx;
  __syncthreads();
  mx = fmaxf(fmaxf(redm[0], redm[1]), fmaxf(redm[2], redm[3]));
  float e[8];
  float sum = 0.f;
#pragma unroll
  for (int i = 0; i < 8; ++i) { e[i] = __expf(s[i] - mx); sum += e[i]; }
#pragma unroll
  for (int o = 32; o > 0; o >>= 1) sum += __shfl_xor(sum, o);
  if (lane == 0) reds[wid] = sum;
  __syncthreads();
  sum = reds[0] + reds[1] + reds[2] + reds[3];
  float inv = 1.0f / sum;
  ushort4 o0, o1;
  o0.x = f2bf(e[0] * inv); o0.y = f2bf(e[1] * inv); o0.z = f2bf(e[2] * inv); o0.w = f2bf(e[3] * inv);
  o1.x = f2bf(e[4] * inv); o1.y = f2bf(e[5] * inv); o1.z = f2bf(e[6] * inv); o1.w = f2bf(e[7] * inv);
  ushort4* dp = reinterpret_cast<ushort4*>(P + row * S_LEN);
  dp[t * 2] = o0;
  dp[t * 2 + 1] = o1;
}

extern "C" void kernel_launch(void* const* d_in, const int* in_sizes, int n_in,
                              void* d_out, int out_size, void* d_ws, size_t ws_size,
                              hipStream_t stream) {
  (void)in_sizes; (void)n_in; (void)out_size;
  const float* x = (const float*)d_in[0];
  const float* Wq = (const float*)d_in[1];
  const float* bq = (const float*)d_in[2];
  const float* Wk = (const float*)d_in[3];
  const float* bk = (const float*)d_in[4];
  const float* Wv = (const float*)d_in[5];
  const float* bv = (const float*)d_in[6];
  float* out = (float*)d_out;

  // workspace layout (bytes), total 140,509,184:
  //   xb    bf16 [8192][1024]  @ 0        (16 MB)  -- reused as Vt after QKV GEMM
  //   Wqkvb bf16 [3072][1024]  @ 16 MB    (6 MB)
  //   QKVb  bf16 [8192][3072]  @ 22 MB    (48 MB)  -- reused as P after scores GEMM
  //   Sb    f32  [4][2048][2048] @ 70 MB  (64 MB)  -- bqkv f32[3072] aliases its head
  if (ws_size < 140509184ull) return;
  char* ws = (char*)d_ws;
  unsigned short* xb    = (unsigned short*)(ws);
  unsigned short* Wqkvb = (unsigned short*)(ws + 16777216);
  unsigned short* QKVb  = (unsigned short*)(ws + 23068672);
  float*          Sb    = (float*)(ws + 73400320);
  float*          bqkv  = (float*)(ws + 73400320);  // alias: dead before Sb written
  unsigned short* Vt    = xb;                        // alias: xb dead after QKV GEMM
  unsigned short* P     = QKVb;                      // alias: QKVb dead after scores GEMM

  // 1) converts to bf16 (+ fused weight concat [Wq;Wk;Wv])
  cvt_kernel<<<dim3(MROWS * DMODEL / 4 / 256), 256, 0, stream>>>(x, (ushort4*)xb, MROWS * DMODEL / 4);
  cvt_kernel<<<dim3(1024), 256, 0, stream>>>(Wq, (ushort4*)Wqkvb, DMODEL * DMODEL / 4);
  cvt_kernel<<<dim3(1024), 256, 0, stream>>>(Wk, (ushort4*)(Wqkvb + 1048576), DMODEL * DMODEL / 4);
  cvt_kernel<<<dim3(1024), 256, 0, stream>>>(Wv, (ushort4*)(Wqkvb + 2097152), DMODEL * DMODEL / 4);
  hipMemcpyAsync(bqkv, bq, 4096, hipMemcpyDeviceToDevice, stream);
  hipMemcpyAsync(bqkv + 1024, bk, 4096, hipMemcpyDeviceToDevice, stream);
  hipMemcpyAsync(bqkv + 2048, bv, 4096, hipMemcpyDeviceToDevice, stream);

  // 2) fused QKV projection: [8192x3072] = x * Wqkv^T + bqkv (M=8192,N=3072,K=1024)
  gemm8<256, 0><<<dim3(12, 32, 1), 512, 0, stream>>>(
      xb, Wqkvb, QKVb, bqkv, 1024, 1024, 3072, 16, 1.f, 0, 0, 0);

  // 3) transpose V cols -> Vt [4][1024][2048]
  transpose_kernel<<<dim3(S_LEN / 32, DMODEL / 32, NBATCH), 256, 0, stream>>>(QKVb, Vt);

  // 4) scores: Sb = Q * K^T * 0.125 (per batch M=N=2048, K=1024; Q/K strided in QKVb)
  gemm8<256, 1><<<dim3(8, 8, 4), 512, 0, stream>>>(
      QKVb, QKVb + 1024, Sb, nullptr, 3072, 3072, 2048, 16, 0.125f,
      (long)S_LEN * 3072, (long)S_LEN * 3072, (long)S_LEN * S_LEN);

  // 5) row softmax -> bf16 P
  softmax_kernel<<<dim3(MROWS), 256, 0, stream>>>(Sb, P);

  // 6) out = P * Vt^T (per batch M=2048, N=1024, K=2048)
  gemm8<128, 2><<<dim3(4, 16, 4), 512, 0, stream>>>(
      P, Vt, out, nullptr, 2048, 2048, 1024, 32, 1.f,
      (long)S_LEN * S_LEN, (long)DMODEL * S_LEN, (long)S_LEN * DMODEL);
}